// Round 1
// baseline (2163.720 us; speedup 1.0000x reference)
//
#include <hip/hip_runtime.h>
#include <cstdint>
#include <cstddef>

typedef _Float16 f16;
typedef _Float16 half8 __attribute__((ext_vector_type(8)));
typedef _Float16 half4 __attribute__((ext_vector_type(4)));
typedef float f32x4 __attribute__((ext_vector_type(4)));

#define NB 256   // batch
#define NT 64    // time
#define NE 1024  // input dim
#define NH 1024  // hidden
#define NZ 512   // out dim
#define NG 4096  // 4*NH

// XOR swizzle for 128B-row LDS tiles: spreads 16 same-column rows across 8
// 16B slots (2 lanes/bank = free per m136). Involution; applied on BOTH the
// global source (inverse) and the LDS read (rule #21: both-sides-or-neither).
__device__ __forceinline__ int swz(int b) { return b ^ (((b >> 7) & 7) << 4); }

#define GL_LDS16(gp, lp)                                                          \
  __builtin_amdgcn_global_load_lds((__attribute__((address_space(1))) void*)(gp), \
                                   (__attribute__((address_space(3))) void*)(lp), \
                                   16, 0, 0)

// ---------------- prep kernels ----------------
__global__ __launch_bounds__(256) void k_cvt(const float* __restrict__ s, f16* __restrict__ d) {
  int i = (blockIdx.x * 256 + threadIdx.x) * 4;
  float4 v = *(const float4*)(s + i);
  half4 h;
  h[0] = (f16)v.x; h[1] = (f16)v.y; h[2] = (f16)v.z; h[3] = (f16)v.w;
  *(half4*)(d + i) = h;
}

__global__ __launch_bounds__(256) void k_addcvt(const float* __restrict__ a,
                                                const float* __restrict__ b,
                                                f16* __restrict__ d) {
  int i = (blockIdx.x * 256 + threadIdx.x) * 4;
  float4 va = *(const float4*)(a + i);
  float4 vb = *(const float4*)(b + i);
  half4 h;
  h[0] = (f16)(va.x + vb.x); h[1] = (f16)(va.y + vb.y);
  h[2] = (f16)(va.z + vb.z); h[3] = (f16)(va.w + vb.w);
  *(half4*)(d + i) = h;
}

__global__ __launch_bounds__(256) void k_bias(const float* be1, const float* be2,
                                              const float* bd1, const float* bd2,
                                              float* be, float* bd) {
  int i = blockIdx.x * 256 + threadIdx.x;  // grid 16 -> 4096
  be[i] = be1[i] + be2[i];
  bd[i] = bd1[i] + bd2[i];
}

// bd0[r] = bd[r] + 0.1 * sum_k W_ih_d[r][k]   (decoder step-0 constant input)
__global__ __launch_bounds__(256) void k_bd0(const float* __restrict__ Wihd,
                                             const float* __restrict__ bd,
                                             float* __restrict__ bd0) {
  int wglob = (blockIdx.x * 256 + threadIdx.x) >> 6;  // grid 64 -> 256 waves
  int lane = threadIdx.x & 63;
  for (int it = 0; it < 16; ++it) {
    int r = it * 256 + wglob;
    const float* row = Wihd + (size_t)r * NH;
    float s = 0.f;
    for (int k = lane; k < NH; k += 64) s += row[k];
    for (int o = 32; o; o >>= 1) s += __shfl_down(s, o);
    if (lane == 0) bd0[r] = bd[r] + 0.1f * s;
  }
}

__global__ __launch_bounds__(256) void k_init(f16* hb, float* c) {
  int i = blockIdx.x * 256 + threadIdx.x;  // grid 1024 -> 262144
  hb[i] = (f16)0.f;
  c[i] = 0.f;
}

// ---------------- generic NT GEMM: C[m,n] = epi(sum_k A[m,k]*B[n,k] + bias[n]) ----------------
// A fp16 [M,K], B fp16 [N,K], 128x128 tile, BK=64, 4 waves 2x2, 4x4 frags/wave.
// EPI 0: outH[m*N+n] = (f16)v            (Xg with bias be)
// EPI 1: out[(m&255)*T*Z + (m>>8)*Z + n] = tanhf(v)   (z-proj, Hs rows are t*256+b)
template <int EPI>
__global__ __launch_bounds__(256) void k_gemm(const f16* __restrict__ A,
                                              const f16* __restrict__ Bm,
                                              const float* __restrict__ bias,
                                              f16* __restrict__ outH,
                                              float* __restrict__ outF,
                                              int M, int N, int K) {
  __shared__ char lds[32768];  // A 16KB @0, B 16KB @16384
  const int tid = threadIdx.x;
  const int lane = tid & 63, wid = tid >> 6;
  const int wm = wid >> 1, wn = wid & 1;
  const int bm = blockIdx.y * 128, bn = blockIdx.x * 128;
  const int l15 = lane & 15, l4 = lane >> 4;

  f32x4 acc[4][4] = {};

  for (int k0 = 0; k0 < K; k0 += 64) {
#pragma unroll
    for (int q = 0; q < 4; ++q) {
      int P = (q * 256 + tid) * 16;       // physical LDS byte (linear dest)
      int L = swz(P);                     // logical byte -> global source
      int row = L >> 7, col = (L & 127) >> 1;
      GL_LDS16(A + (size_t)(bm + row) * K + k0 + col, lds + P);
      GL_LDS16(Bm + (size_t)(bn + row) * K + k0 + col, lds + 16384 + P);
    }
    __syncthreads();
#pragma unroll
    for (int kk = 0; kk < 2; ++kk) {
      half8 af[4], bf[4];
#pragma unroll
      for (int mi = 0; mi < 4; ++mi) {
        int L = (wm * 64 + mi * 16 + l15) * 128 + (kk * 32 + l4 * 8) * 2;
        af[mi] = *(const half8*)(lds + swz(L));
      }
#pragma unroll
      for (int ni = 0; ni < 4; ++ni) {
        int L = (wn * 64 + ni * 16 + l15) * 128 + (kk * 32 + l4 * 8) * 2;
        bf[ni] = *(const half8*)(lds + 16384 + swz(L));
      }
#pragma unroll
      for (int mi = 0; mi < 4; ++mi)
#pragma unroll
        for (int ni = 0; ni < 4; ++ni)
          acc[mi][ni] = __builtin_amdgcn_mfma_f32_16x16x32_f16(af[mi], bf[ni], acc[mi][ni], 0, 0, 0);
    }
    __syncthreads();
  }

#pragma unroll
  for (int mi = 0; mi < 4; ++mi)
#pragma unroll
    for (int ni = 0; ni < 4; ++ni)
#pragma unroll
      for (int e = 0; e < 4; ++e) {
        int m = bm + wm * 64 + mi * 16 + l4 * 4 + e;
        int n = bn + wn * 64 + ni * 16 + l15;
        float v = acc[mi][ni][e] + bias[n];
        if constexpr (EPI == 0) {
          outH[(size_t)m * N + n] = (f16)v;
        } else {
          int b = m & 255, t = m >> 8;
          outF[(size_t)b * (NT * NZ) + t * NZ + n] = tanhf(v);
        }
      }
}

// ---------------- fused LSTM step: gates GEMM + cell ----------------
// grid (NH/32, NB/32) = (32,8) = 256 wgs. Wave w computes gate w's 32x32 tile.
// gates[b,n] = sum_k hin[b,k]*W[n,k] (+ pregate from Xg | + bias), then cell.
__global__ __launch_bounds__(256) void k_step(const f16* __restrict__ hin,  // [256,1024]
                                              float* __restrict__ c,        // [256,1024] in-place
                                              const f16* __restrict__ W,    // [4096,1024]
                                              const f16* __restrict__ pg,   // Xg+t*4096 or null
                                              int pgStride,                 // NT*NG
                                              const float* __restrict__ bias,  // [4096] or null
                                              f16* __restrict__ hout) {     // [256,1024]
  __shared__ char lds[20480];  // A 4KB @0; B 16KB @4096 (reused for gate exchange)
  const int tid = threadIdx.x, lane = tid & 63, wid = tid >> 6;
  const int jt = blockIdx.x, bt = blockIdx.y;
  const int l15 = lane & 15, l4 = lane >> 4;

  f32x4 acc[2][2] = {};

  for (int k0 = 0; k0 < 1024; k0 += 64) {
    {  // A: 32x64 fp16 tile of hin
      int P = tid * 16;
      int L = swz(P);
      int row = L >> 7, col = (L & 127) >> 1;
      GL_LDS16(hin + (size_t)(bt * 32 + row) * NH + k0 + col, lds + P);
    }
#pragma unroll
    for (int q = 0; q < 4; ++q) {  // B: wave w stages its gate's 32x64 tile
      int P = (q * 64 + lane) * 16;
      int L = swz(P);
      int row = L >> 7, col = (L & 127) >> 1;
      GL_LDS16(W + (size_t)(wid * NH + jt * 32 + row) * NH + k0 + col,
               lds + 4096 + wid * 4096 + P);
    }
    __syncthreads();
#pragma unroll
    for (int kk = 0; kk < 2; ++kk) {
      half8 af[2], bf[2];
#pragma unroll
      for (int mi = 0; mi < 2; ++mi) {
        int L = (mi * 16 + l15) * 128 + (kk * 32 + l4 * 8) * 2;
        af[mi] = *(const half8*)(lds + swz(L));
      }
#pragma unroll
      for (int ni = 0; ni < 2; ++ni) {
        int L = (ni * 16 + l15) * 128 + (kk * 32 + l4 * 8) * 2;
        bf[ni] = *(const half8*)(lds + 4096 + wid * 4096 + swz(L));
      }
#pragma unroll
      for (int mi = 0; mi < 2; ++mi)
#pragma unroll
        for (int ni = 0; ni < 2; ++ni)
          acc[mi][ni] = __builtin_amdgcn_mfma_f32_16x16x32_f16(af[mi], bf[ni], acc[mi][ni], 0, 0, 0);
    }
    __syncthreads();
  }

  // exchange gates via LDS: float [4][32][32] at offset 4096
  float* gl = (float*)(lds + 4096);
#pragma unroll
  for (int mi = 0; mi < 2; ++mi)
#pragma unroll
    for (int ni = 0; ni < 2; ++ni)
#pragma unroll
      for (int e = 0; e < 4; ++e) {
        int r = mi * 16 + l4 * 4 + e;   // batch-local row
        int j = ni * 16 + l15;          // unit-local col
        gl[wid * 1024 + r * 32 + j] = acc[mi][ni][e];
      }
  __syncthreads();

#pragma unroll
  for (int e = 0; e < 4; ++e) {
    int idx = e * 256 + tid;
    int r = idx >> 5, j = idx & 31;
    float g0 = gl[0 * 1024 + r * 32 + j];
    float g1 = gl[1 * 1024 + r * 32 + j];
    float g2 = gl[2 * 1024 + r * 32 + j];
    float g3 = gl[3 * 1024 + r * 32 + j];
    int brow = bt * 32 + r;
    int ncol = jt * 32 + j;
    if (pg) {
      const f16* p = pg + (size_t)brow * pgStride + ncol;
      g0 += (float)p[0]; g1 += (float)p[1024]; g2 += (float)p[2048]; g3 += (float)p[3072];
    }
    if (bias) {
      g0 += bias[ncol]; g1 += bias[1024 + ncol]; g2 += bias[2048 + ncol]; g3 += bias[3072 + ncol];
    }
    float i_ = 1.f / (1.f + __expf(-g0));
    float f_ = 1.f / (1.f + __expf(-g1));
    float gg = tanhf(g2);
    float o_ = 1.f / (1.f + __expf(-g3));
    size_t ci = (size_t)brow * NH + ncol;
    float c2 = f_ * c[ci] + i_ * gg;
    c[ci] = c2;
    hout[ci] = (f16)(o_ * tanhf(c2));
  }
}

// ---------------- workspace layout ----------------
static const size_t OFF_X16  = 0;
static const size_t OFF_WIHE = OFF_X16 + (size_t)NB * NT * NE * 2;
static const size_t OFF_WHHE = OFF_WIHE + (size_t)NG * NH * 2;
static const size_t OFF_WSUM = OFF_WHHE + (size_t)NG * NH * 2;
static const size_t OFF_WHHD = OFF_WSUM + (size_t)NG * NH * 2;
static const size_t OFF_WZ   = OFF_WHHD + (size_t)NG * NH * 2;
static const size_t OFF_BE   = OFF_WZ + (size_t)NZ * NH * 2;
static const size_t OFF_BD   = OFF_BE + NG * 4;
static const size_t OFF_BD0  = OFF_BD + NG * 4;
static const size_t OFF_HB0  = OFF_BD0 + NG * 4;
static const size_t OFF_HB1  = OFF_HB0 + (size_t)NB * NH * 2;
static const size_t OFF_C    = OFF_HB1 + (size_t)NB * NH * 2;
static const size_t OFF_XG   = OFF_C + (size_t)NB * NH * 4;   // Xg [B][T][4H] fp16; Hs aliases it
static const size_t WS_TOTAL = OFF_XG + (size_t)NB * NT * NG * 2;  // ~195 MiB

extern "C" void kernel_launch(void* const* d_in, const int* in_sizes, int n_in,
                              void* d_out, int out_size, void* d_ws, size_t ws_size,
                              hipStream_t stream) {
  (void)in_sizes; (void)n_in; (void)out_size;
  const float* x    = (const float*)d_in[0];
  const float* Wihe = (const float*)d_in[1];
  const float* Whhe = (const float*)d_in[2];
  const float* bihe = (const float*)d_in[3];
  const float* bhhe = (const float*)d_in[4];
  const float* Wihd = (const float*)d_in[5];
  const float* Whhd = (const float*)d_in[6];
  const float* bihd = (const float*)d_in[7];
  const float* bhhd = (const float*)d_in[8];
  const float* Wzf  = (const float*)d_in[9];
  const float* bz   = (const float*)d_in[10];
  float* out = (float*)d_out;

  if (ws_size < WS_TOTAL) return;  // fail loudly (wrong output) rather than corrupt

  char* ws = (char*)d_ws;
  f16* x16    = (f16*)(ws + OFF_X16);
  f16* Wihe16 = (f16*)(ws + OFF_WIHE);
  f16* Whhe16 = (f16*)(ws + OFF_WHHE);
  f16* Wsum16 = (f16*)(ws + OFF_WSUM);
  f16* Whhd16 = (f16*)(ws + OFF_WHHD);
  f16* Wz16   = (f16*)(ws + OFF_WZ);
  float* be   = (float*)(ws + OFF_BE);
  float* bd   = (float*)(ws + OFF_BD);
  float* bd0  = (float*)(ws + OFF_BD0);
  f16* hb0    = (f16*)(ws + OFF_HB0);
  f16* hb1    = (f16*)(ws + OFF_HB1);
  float* c    = (float*)(ws + OFF_C);
  f16* Xg     = (f16*)(ws + OFF_XG);
  f16* Hs     = Xg;  // decoder h history overlays dead Xg

  // prep
  k_cvt<<<(NB * NT * NE) / 1024, 256, 0, stream>>>(x, x16);
  k_cvt<<<(NG * NH) / 1024, 256, 0, stream>>>(Wihe, Wihe16);
  k_cvt<<<(NG * NH) / 1024, 256, 0, stream>>>(Whhe, Whhe16);
  k_cvt<<<(NG * NH) / 1024, 256, 0, stream>>>(Whhd, Whhd16);
  k_cvt<<<(NZ * NH) / 1024, 256, 0, stream>>>(Wzf, Wz16);
  k_addcvt<<<(NG * NH) / 1024, 256, 0, stream>>>(Wihd, Whhd, Wsum16);
  k_bias<<<NG / 256, 256, 0, stream>>>(bihe, bhhe, bihd, bhhd, be, bd);
  k_bd0<<<64, 256, 0, stream>>>(Wihd, bd, bd0);
  k_init<<<(NB * NH) / 256, 256, 0, stream>>>(hb0, c);

  // Xg = x @ W_ih_e^T + be   -> fp16 [B][T][4H]
  dim3 gx(NG / 128, (NB * NT) / 128);
  k_gemm<0><<<gx, 256, 0, stream>>>(x16, Wihe16, be, Xg, nullptr, NB * NT, NG, NE);

  // encoder: 64 fused steps, h ping-pong, c in place
  for (int t = 0; t < NT; ++t) {
    const f16* hi = (t & 1) ? hb1 : hb0;
    f16* ho = (t & 1) ? hb0 : hb1;
    k_step<<<dim3(NH / 32, NB / 32), 256, 0, stream>>>(hi, c, Whhe16, Xg + t * NG, NT * NG,
                                                       nullptr, ho);
  }
  // after t=63 the encoder h lives in hb0

  // decoder: step0 uses W_hh_d + bd0 (0.1-input folded); t>=1 uses (W_ih_d+W_hh_d) + bd
  for (int t = 0; t < NT; ++t) {
    const f16* hi = (t == 0) ? hb0 : Hs + (size_t)(t - 1) * NB * NH;
    k_step<<<dim3(NH / 32, NB / 32), 256, 0, stream>>>(
        hi, c, (t == 0) ? Whhd16 : Wsum16, nullptr, 0, (t == 0) ? bd0 : bd,
        Hs + (size_t)t * NB * NH);
  }

  // z = tanh(Hs @ Wz^T + bz), scattered [t*256+b] -> out[b][t][:]
  dim3 gz(NZ / 128, (NB * NT) / 128);
  k_gemm<1><<<gz, 256, 0, stream>>>(Hs, Wz16, bz, nullptr, out, NB * NT, NZ, NH);
}